// Round 8
// baseline (316.773 us; speedup 1.0000x reference)
//
#include <hip/hip_runtime.h>
#include <hip/hip_bf16.h>

#define B_    4
#define NUM   1024
#define CH    256
#define HEADS 4
#define DK    64
#define LDK   72   // padded LDS row stride in bf16 elements (2-way bank alias = free)
#define NJC   8    // j-chunks per (b,h,i-tile); chunk = 128 cols = 2 j-tiles

typedef __hip_bfloat16 bf;
typedef __attribute__((ext_vector_type(8))) short short8;
typedef __attribute__((ext_vector_type(4))) float f32x4;
typedef unsigned long long u64;

__device__ inline bf tobf(float v) { return __float2bfloat16(v); }

// ---------------- zero the topk union masks (float 0/1) ----------------
__global__ void zero_vec_kernel(float* v1, float* v2) {
  int i = blockIdx.x * blockDim.x + threadIdx.x;
  if (i < NUM) { v1[i] = 0.f; v2[i] = 0.f; }
}

// ---------------- pack (mroi && smask_j) into bit-words: pk[row][jw] ----------------
__global__ __launch_bounds__(256) void pack_kernel(
    const int* __restrict__ mroi, const int* __restrict__ smask,
    u64* __restrict__ pk) {
  int row = blockIdx.x * 4 + (threadIdx.x >> 6);
  int lane = threadIdx.x & 63;
  int b = row >> 10;
  const int* mr = &mroi[(size_t)row * NUM];
  const int* sm = &smask[b * NUM];
  #pragma unroll
  for (int w = 0; w < 16; ++w) {
    int j = w * 64 + lane;
    u64 word = __ballot((mr[j] != 0) && (sm[j] != 0));
    if (lane == 0) pk[(size_t)row * 16 + w] = word;
  }
}

// stage a 64x64 fp32 global tile -> bf16 LDS tile [64][LDK]
__device__ inline void stage_tile(const float* __restrict__ src, size_t row0,
                                  int col0, int rowstride, bf (*dst)[LDK], int tid) {
  int r = tid >> 4, c4 = (tid & 15) * 4;
  #pragma unroll
  for (int it = 0; it < 4; ++it) {
    int row = r + it * 16;
    const float4 v = *(const float4*)&src[(row0 + row) * (size_t)rowstride + col0 + c4];
    union { bf h4[4]; short4 s4; } u;
    u.h4[0] = tobf(v.x); u.h4[1] = tobf(v.y); u.h4[2] = tobf(v.z); u.h4[3] = tobf(v.w);
    *(short4*)&dst[row][c4] = u.s4;
  }
}

// load this lane's A-fragments (2 k-blocks) straight from global into registers
__device__ inline void load_afrag(const float* __restrict__ arow, int quad, short8 af[2]) {
  #pragma unroll
  for (int kb = 0; kb < 2; ++kb) {
    const float4 v0 = *(const float4*)&arow[kb * 32 + quad * 8];
    const float4 v1 = *(const float4*)&arow[kb * 32 + quad * 8 + 4];
    union { bf hh[8]; short8 s; } u;
    u.hh[0] = tobf(v0.x); u.hh[1] = tobf(v0.y); u.hh[2] = tobf(v0.z); u.hh[3] = tobf(v0.w);
    u.hh[4] = tobf(v1.x); u.hh[5] = tobf(v1.y); u.hh[6] = tobf(v1.z); u.hh[7] = tobf(v1.w);
    af[kb] = u.s;
  }
}

// ---------------- gts = relu(gt_feat @ gt_w^T + gt_b), bf16 MFMA ----------------
__global__ __launch_bounds__(256) void gts_kernel(
    const float* __restrict__ gf, const float* __restrict__ gw,
    const float* __restrict__ gb, float* __restrict__ out) {
  __shared__ __align__(16) bf As[64][LDK];
  __shared__ __align__(16) bf Bs[64][LDK];
  const int m0 = blockIdx.x * 64, n0 = blockIdx.y * 64;
  const int tid = threadIdx.x, lane = tid & 63, w = tid >> 6;
  const int m = lane & 15, quad = lane >> 4;
  f32x4 acc[4] = {{0.f,0.f,0.f,0.f},{0.f,0.f,0.f,0.f},{0.f,0.f,0.f,0.f},{0.f,0.f,0.f,0.f}};
  for (int k0 = 0; k0 < 256; k0 += 64) {
    __syncthreads();
    stage_tile(gf, m0, k0, 256, As, tid);
    stage_tile(gw, n0, k0, 256, Bs, tid);
    __syncthreads();
    #pragma unroll
    for (int kb = 0; kb < 2; ++kb) {
      short8 a = *(const short8*)&As[w * 16 + m][kb * 32 + quad * 8];
      #pragma unroll
      for (int nt = 0; nt < 4; ++nt) {
        short8 bb = *(const short8*)&Bs[nt * 16 + m][kb * 32 + quad * 8];
        acc[nt] = __builtin_amdgcn_mfma_f32_16x16x32_bf16(a, bb, acc[nt], 0, 0, 0);
      }
    }
  }
  #pragma unroll
  for (int nt = 0; nt < 4; ++nt)
    #pragma unroll
    for (int r = 0; r < 4; ++r) {
      int row = m0 + w * 16 + quad * 4 + r, col = n0 + nt * 16 + m;
      out[(size_t)row * 256 + col] = fmaxf(acc[nt][r] + gb[col], 0.f);
    }
}

// ---------------- grouped 1x1 conv + relu (fp32), dual write w/ diag seed ----------------
// out = relu(conv); out2 = relu(conv) * (seedbase + 0.25*[smask==0])
__global__ __launch_bounds__(256) void conv_kernel(
    const float* __restrict__ x, const float* __restrict__ w,
    const float* __restrict__ bias, const int* __restrict__ smask,
    float seedbase, float* __restrict__ out, float* __restrict__ out2) {
  __shared__ float Xs[64][65];
  __shared__ float Wsm[64][65];
  const int m0 = blockIdx.x * 64, g = blockIdx.y;
  const int tid = threadIdx.x, tx = tid & 15, ty = tid >> 4;
  #pragma unroll
  for (int l = 0; l < 16; ++l) {
    int idx = tid + l * 256; int r = idx >> 6, c = idx & 63;
    Xs[r][c] = x[(size_t)(m0 + r) * CH + g * DK + c];
    Wsm[r][c] = w[g * DK * DK + r * DK + c];
  }
  __syncthreads();
  float acc[4][4] = {};
  #pragma unroll 8
  for (int k = 0; k < DK; ++k) {
    float av[4], bv[4];
    #pragma unroll
    for (int i = 0; i < 4; ++i) av[i] = Xs[ty * 4 + i][k];
    #pragma unroll
    for (int j = 0; j < 4; ++j) bv[j] = Wsm[tx * 4 + j][k];
    #pragma unroll
    for (int i = 0; i < 4; ++i)
      #pragma unroll
      for (int j = 0; j < 4; ++j) acc[i][j] += av[i] * bv[j];
  }
  #pragma unroll
  for (int i = 0; i < 4; ++i) {
    int row = m0 + ty * 4 + i;
    float seed = seedbase + ((smask[row] == 0) ? 0.25f : 0.f);
    #pragma unroll
    for (int j = 0; j < 4; ++j) {
      int o = g * DK + tx * 4 + j;
      size_t idx = (size_t)row * CH + o;
      float v = fmaxf(acc[i][j] + bias[o], 0.f);
      out[idx] = v;
      out2[idx] = v * seed;
    }
  }
}

// ---------------- per-node per-head reciprocal L2 norms ----------------
__global__ void norms_kernel(const float* __restrict__ x, float* __restrict__ rn) {
  int bn = blockIdx.x;
  int t = threadIdx.x;
  float v = x[(size_t)bn * CH + t];
  float s = v * v;
  #pragma unroll
  for (int off = 32; off; off >>= 1) s += __shfl_down(s, off, 64);
  if ((t & 63) == 0) rn[bn * HEADS + (t >> 6)] = 1.0f / fmaxf(sqrtf(s), 1e-4f);
}

// top-4 insert, jax-stable tie-break (higher value first; equal value -> lower index)
__device__ inline void ins4(float v, int id, float tv[4], int tj[4]) {
  if (v < tv[3] || (v == tv[3] && id > tj[3])) return;
  tv[3] = v; tj[3] = id;
  #pragma unroll
  for (int k = 3; k > 0; --k) {
    bool sw = (tv[k] > tv[k - 1]) || (tv[k] == tv[k - 1] && tj[k] < tj[k - 1]);
    if (sw) {
      float fv = tv[k]; tv[k] = tv[k - 1]; tv[k - 1] = fv;
      int ti = tj[k]; tj[k] = tj[k - 1]; tj[k - 1] = ti;
    }
  }
}

// ---------------- scores once: top-4 candidates + masked Ws -> global ----------------
// Per block: one 64-row i-tile x one 128-col j-chunk (2 j-tiles).
// Ws[i][j] = pkbit * relu(dot*rnj) * rni4  (rni4 includes the /4), stored bf16.
// Ranking value relu(dot*rnj): same order/ties as cos (rni>0 row-constant).
__global__ __launch_bounds__(256) void score_kernel(
    const float* __restrict__ x, const float* __restrict__ rn,
    const u64* __restrict__ pk, bf* __restrict__ WS,
    float* __restrict__ candV, int* __restrict__ candI) {
  __shared__ __align__(16) char SM[25088];
  bf (*Xj)[LDK] = (bf(*)[LDK])SM;                 // 9216 B
  bf (*Ws)[LDK] = (bf(*)[LDK])(SM + 9216);        // 9216 B
  float (*cV)[65] = (float(*)[65])SM;             // overlay after j-loop: 16640 B
  unsigned short (*cI)[66] = (unsigned short(*)[66])(SM + 16640);  // 8448 B
  const int b = blockIdx.z, h = blockIdx.y;
  const int it = blockIdx.x >> 3, jc = blockIdx.x & 7;
  const int i0 = it * 64;
  const int tid = threadIdx.x, lane = tid & 63, w = tid >> 6;
  const int m = lane & 15, quad = lane >> 4;

  short8 afrag[2];
  load_afrag(&x[((size_t)b * NUM + i0 + w * 16 + m) * CH + h * DK], quad, afrag);
  float rni4[4];
  #pragma unroll
  for (int r = 0; r < 4; ++r)
    rni4[r] = 0.25f * rn[((size_t)b * NUM + i0 + w * 16 + quad * 4 + r) * HEADS + h];

  float tv[4][4]; int tj[4][4];
  #pragma unroll
  for (int r = 0; r < 4; ++r)
    #pragma unroll
    for (int q = 0; q < 4; ++q) { tv[r][q] = -1.f; tj[r][q] = 0x7fffffff; }

  for (int jt = 0; jt < 2; ++jt) {
    int j0 = jc * 128 + jt * 64;
    __syncthreads();
    stage_tile(x, (size_t)b * NUM + j0, h * DK, CH, Xj, tid);
    u64 wr[4];
    #pragma unroll
    for (int r = 0; r < 4; ++r)
      wr[r] = pk[((size_t)b * NUM + i0 + w * 16 + quad * 4 + r) * 16 + (j0 >> 6)];
    __syncthreads();
    #pragma unroll
    for (int nt = 0; nt < 4; ++nt) {
      f32x4 acc = {0.f, 0.f, 0.f, 0.f};
      #pragma unroll
      for (int kb = 0; kb < 2; ++kb) {
        short8 bb = *(const short8*)&Xj[nt * 16 + m][kb * 32 + quad * 8];
        acc = __builtin_amdgcn_mfma_f32_16x16x32_bf16(afrag[kb], bb, acc, 0, 0, 0);
      }
      int j = j0 + nt * 16 + m;
      float rnj = rn[((size_t)b * NUM + j) * HEADS + h];
      #pragma unroll
      for (int r = 0; r < 4; ++r) {
        float v = fmaxf(acc[r] * rnj, 0.f);
        ins4(v, j, tv[r], tj[r]);
        bool bit = (wr[r] >> (nt * 16 + m)) & 1ull;
        Ws[w * 16 + quad * 4 + r][nt * 16 + m] = tobf(bit ? v * rni4[r] : 0.f);
      }
    }
    // same-wave stripe copy LDS -> global WS (rows w*16..w*16+15), coalesced 16B
    {
      int row = w * 16 + (lane >> 2), colb = (lane & 3) * 16;
      short8 s0 = *(const short8*)&Ws[row][colb];
      short8 s1 = *(const short8*)&Ws[row][colb + 8];
      bf* dst = &WS[((size_t)(b * HEADS + h) * NUM + i0 + row) * NUM + j0 + colb];
      *(short8*)dst = s0;
      *(short8*)(dst + 8) = s1;
    }
  }
  __syncthreads();  // Xj/Ws dead; overlay as cV/cI
  #pragma unroll
  for (int r = 0; r < 4; ++r)
    #pragma unroll
    for (int q = 0; q < 4; ++q) {
      cV[w * 16 + quad * 4 + r][m * 4 + q] = tv[r][q];
      cI[w * 16 + quad * 4 + r][m * 4 + q] = (unsigned short)(tj[r][q] & 0xffff);
    }
  __syncthreads();
  if (tid < 64) {
    float fv[4] = {-1.f, -1.f, -1.f, -1.f};
    int fi[4] = {0x7fffffff, 0x7fffffff, 0x7fffffff, 0x7fffffff};
    for (int q = 0; q < 64; ++q) ins4(cV[tid][q], (int)cI[tid][q], fv, fi);
    size_t base = (size_t)((((b * HEADS + h) * 16 + it) * NJC + jc) * 64 + tid) * 4;
    #pragma unroll
    for (int q = 0; q < 4; ++q) { candV[base + q] = fv[q]; candI[base + q] = fi[q]; }
  }
}

// ---------------- merge NJC chunk candidates per row -> union into vec ----------------
__global__ __launch_bounds__(256) void topk_merge_kernel(
    const float* __restrict__ candV, const int* __restrict__ candI,
    float* __restrict__ vec) {
  int t = blockIdx.x * 256 + threadIdx.x;   // t = bhit*64 + rl
  int bhit = t >> 6, rl = t & 63;
  float fv[4] = {-1.f, -1.f, -1.f, -1.f};
  int fi[4] = {0x7fffffff, 0x7fffffff, 0x7fffffff, 0x7fffffff};
  #pragma unroll
  for (int jc = 0; jc < NJC; ++jc) {
    size_t base = (size_t)(((bhit) * NJC + jc) * 64 + rl) * 4;
    #pragma unroll
    for (int q = 0; q < 4; ++q) ins4(candV[base + q], candI[base + q], fv, fi);
  }
  #pragma unroll
  for (int q = 0; q < 4; ++q) vec[fi[q]] = 1.0f;  // benign race, all write 1
}

// ---------------- PV: om[i,c] += sum_j WS[i,j] * vec_j * conv[j,c] ----------------
// A-frags straight from global WS (bf16, row-major). Diag seed already in out.
__global__ __launch_bounds__(256) void pv_kernel(
    const bf* __restrict__ WS, const float* __restrict__ conv,
    const float* __restrict__ vec, float* __restrict__ out) {
  __shared__ __align__(16) bf Cv[64][LDK];
  const int b = blockIdx.z, h = blockIdx.y;
  const int it = blockIdx.x >> 3, jc = blockIdx.x & 7;
  const int i0 = it * 64;
  const int tid = threadIdx.x, lane = tid & 63, w = tid >> 6;
  const int m = lane & 15, quad = lane >> 4;

  const bf* arow = &WS[((size_t)(b * HEADS + h) * NUM + i0 + w * 16 + m) * NUM];
  f32x4 om[4] = {{0.f,0.f,0.f,0.f},{0.f,0.f,0.f,0.f},{0.f,0.f,0.f,0.f},{0.f,0.f,0.f,0.f}};

  for (int jt = 0; jt < 2; ++jt) {
    int j0 = jc * 128 + jt * 64;
    __syncthreads();
    {  // vec-masked conv^T tile
      int jr = tid >> 4, c4 = tid & 15;
      #pragma unroll
      for (int itt = 0; itt < 4; ++itt) {
        int j = jr + itt * 16;
        float vm = vec[j0 + j];
        const float4 v = *(const float4*)&conv[((size_t)b * NUM + j0 + j) * CH + h * DK + c4 * 4];
        Cv[c4 * 4 + 0][j] = tobf(v.x * vm);
        Cv[c4 * 4 + 1][j] = tobf(v.y * vm);
        Cv[c4 * 4 + 2][j] = tobf(v.z * vm);
        Cv[c4 * 4 + 3][j] = tobf(v.w * vm);
      }
    }
    __syncthreads();
    #pragma unroll
    for (int kb = 0; kb < 2; ++kb) {
      short8 a = *(const short8*)&arow[j0 + kb * 32 + quad * 8];
      #pragma unroll
      for (int ct = 0; ct < 4; ++ct) {
        short8 bb = *(const short8*)&Cv[ct * 16 + m][kb * 32 + quad * 8];
        om[ct] = __builtin_amdgcn_mfma_f32_16x16x32_bf16(a, bb, om[ct], 0, 0, 0);
      }
    }
  }
  #pragma unroll
  for (int ct = 0; ct < 4; ++ct)
    #pragma unroll
    for (int r = 0; r < 4; ++r) {
      size_t idx = ((size_t)b * NUM + i0 + w * 16 + quad * 4 + r) * CH + h * DK + ct * 16 + m;
      atomicAdd(&out[idx], om[ct][r]);
    }
}

// ---------------- LayerNorm + final outputs (in-place on d_out regions) ----------------
__global__ __launch_bounds__(256) void final_kernel(
    float* __restrict__ ybnf, float* __restrict__ out0,
    const float* __restrict__ lnw, const float* __restrict__ lnb) {
  __shared__ float r1[4];
  __shared__ float r2[4];
  int bn = blockIdx.x;
  int c = threadIdx.x;
  size_t idx = (size_t)bn * CH + c;
  float y = ybnf[idx];
  float x2v = out0[idx];
  float s = y;
  #pragma unroll
  for (int off = 32; off; off >>= 1) s += __shfl_down(s, off, 64);
  int wave = c >> 6, lane = c & 63;
  if (lane == 0) r1[wave] = s;
  __syncthreads();
  float mu = (r1[0] + r1[1] + r1[2] + r1[3]) * (1.f / 256.f);
  float d = y - mu;
  float s2 = d * d;
  #pragma unroll
  for (int off = 32; off; off >>= 1) s2 += __shfl_down(s2, off, 64);
  if (lane == 0) r2[wave] = s2;
  __syncthreads();
  float var = (r2[0] + r2[1] + r2[2] + r2[3]) * (1.f / 256.f);
  float nf = d * rsqrtf(var + 1e-6f) * lnw[c] + lnb[c];
  ybnf[idx] = nf;
  out0[idx] = x2v + nf;
}

extern "C" void kernel_launch(void* const* d_in, const int* in_sizes, int n_in,
                              void* d_out, int out_size, void* d_ws, size_t ws_size,
                              hipStream_t stream) {
  const float* input = (const float*)d_in[0];
  const int* mroi = (const int*)d_in[1];
  const int* smask = (const int*)d_in[2];
  const float* gt_feat = (const float*)d_in[3];
  const float* w1 = (const float*)d_in[4];
  const float* b1 = (const float*)d_in[5];
  const float* w2 = (const float*)d_in[6];
  const float* b2 = (const float*)d_in[7];
  const float* gt_w = (const float*)d_in[8];
  const float* gt_b = (const float*)d_in[9];
  const float* lnw = (const float*)d_in[10];
  const float* lnb = (const float*)d_in[11];

  const size_t SEG = (size_t)B_ * NUM * CH;  // 1048576 elements
  float* out0 = (float*)d_out;     // finally: out2^T + node_feat ; interim: X2 (conv2)
  float* gts = out0 + SEG;         // gts output (final from the start)
  float* nfreg = out0 + 2 * SEG;   // finally: node_feat ; interim: X1 then Yb

  // ws: F1 4MB | RN 64KB | VEC 8KB | candV 8MB | candI 8MB | PK 512KB | WS 32MB ~= 53MB
  float* F1 = (float*)d_ws;
  float* RN = F1 + SEG;
  float* VEC1 = RN + (size_t)B_ * NUM * HEADS;
  float* VEC2 = VEC1 + NUM;
  float* candV = VEC2 + NUM;
  const size_t NCAND = (size_t)B_ * HEADS * 16 * NJC * 64 * 4;
  int* candI = (int*)(candV + NCAND);
  u64* PK = (u64*)(candI + NCAND);
  bf* WS = (bf*)(PK + (size_t)B_ * NUM * 16);

  float* X1 = nfreg;  // conv1 output (F1 seeded = X1*(1+0.25*[sm==0]))
  float* X2 = out0;   // conv2 output lives in out0 region until final_kernel
  float* Yb = nfreg;  // o2m accumulator (seeded = 0.25*[sm==0]*X2, overwrites dead X1)

  zero_vec_kernel<<<4, 256, 0, stream>>>(VEC1, VEC2);
  pack_kernel<<<1024, 256, 0, stream>>>(mroi, smask, PK);
  gts_kernel<<<dim3(64, 4), 256, 0, stream>>>(gt_feat, gt_w, gt_b, gts);

  // stage 1
  conv_kernel<<<dim3(64, 4), 256, 0, stream>>>(input, w1, b1, smask, 1.0f, X1, F1);
  norms_kernel<<<4096, 256, 0, stream>>>(input, RN);
  score_kernel<<<dim3(16 * NJC, HEADS, B_), 256, 0, stream>>>(input, RN, PK, WS, candV, candI);
  topk_merge_kernel<<<64, 256, 0, stream>>>(candV, candI, VEC1);
  pv_kernel<<<dim3(16 * NJC, HEADS, B_), 256, 0, stream>>>(WS, X1, VEC1, F1);

  // stage 2
  conv_kernel<<<dim3(64, 4), 256, 0, stream>>>(F1, w2, b2, smask, 0.0f, X2, Yb);
  norms_kernel<<<4096, 256, 0, stream>>>(F1, RN);
  score_kernel<<<dim3(16 * NJC, HEADS, B_), 256, 0, stream>>>(F1, RN, PK, WS, candV, candI);
  topk_merge_kernel<<<64, 256, 0, stream>>>(candV, candI, VEC2);
  pv_kernel<<<dim3(16 * NJC, HEADS, B_), 256, 0, stream>>>(WS, X2, VEC2, Yb);

  final_kernel<<<4096, 256, 0, stream>>>(Yb, X2, lnw, lnb);
}

// Round 9
// 310.445 us; speedup vs baseline: 1.0204x; 1.0204x over previous
//
#include <hip/hip_runtime.h>
#include <hip/hip_bf16.h>

#define B_    4
#define NUM   1024
#define CH    256
#define HEADS 4
#define DK    64
#define LDK   72   // padded LDS row stride in bf16 elements (2-way bank alias = free)
#define NJC   8    // j-chunks per (b,h,i-tile); chunk = 128 cols = 2 j-tiles

typedef __hip_bfloat16 bf;
typedef __attribute__((ext_vector_type(8))) short short8;
typedef __attribute__((ext_vector_type(4))) float f32x4;
typedef unsigned long long u64;

__device__ inline bf tobf(float v) { return __float2bfloat16(v); }

// ---------------- zero the topk union masks (float 0/1) ----------------
__global__ void zero_vec_kernel(float* v1, float* v2) {
  int i = blockIdx.x * blockDim.x + threadIdx.x;
  if (i < NUM) { v1[i] = 0.f; v2[i] = 0.f; }
}

// ---------------- pack (mroi && smask_j) into bit-words: pk[row][jw] ----------------
__global__ __launch_bounds__(256) void pack_kernel(
    const int* __restrict__ mroi, const int* __restrict__ smask,
    u64* __restrict__ pk) {
  int row = blockIdx.x * 4 + (threadIdx.x >> 6);
  int lane = threadIdx.x & 63;
  int b = row >> 10;
  const int* mr = &mroi[(size_t)row * NUM];
  const int* sm = &smask[b * NUM];
  #pragma unroll
  for (int w = 0; w < 16; ++w) {
    int j = w * 64 + lane;
    u64 word = __ballot((mr[j] != 0) && (sm[j] != 0));
    if (lane == 0) pk[(size_t)row * 16 + w] = word;
  }
}

// stage a 64x64 fp32 global tile -> bf16 LDS tile [64][LDK]
__device__ inline void stage_tile(const float* __restrict__ src, size_t row0,
                                  int col0, int rowstride, bf (*dst)[LDK], int tid) {
  int r = tid >> 4, c4 = (tid & 15) * 4;
  #pragma unroll
  for (int it = 0; it < 4; ++it) {
    int row = r + it * 16;
    const float4 v = *(const float4*)&src[(row0 + row) * (size_t)rowstride + col0 + c4];
    union { bf h4[4]; short4 s4; } u;
    u.h4[0] = tobf(v.x); u.h4[1] = tobf(v.y); u.h4[2] = tobf(v.z); u.h4[3] = tobf(v.w);
    *(short4*)&dst[row][c4] = u.s4;
  }
}

// load this lane's A-fragments (2 k-blocks) straight from global into registers
__device__ inline void load_afrag(const float* __restrict__ arow, int quad, short8 af[2]) {
  #pragma unroll
  for (int kb = 0; kb < 2; ++kb) {
    const float4 v0 = *(const float4*)&arow[kb * 32 + quad * 8];
    const float4 v1 = *(const float4*)&arow[kb * 32 + quad * 8 + 4];
    union { bf hh[8]; short8 s; } u;
    u.hh[0] = tobf(v0.x); u.hh[1] = tobf(v0.y); u.hh[2] = tobf(v0.z); u.hh[3] = tobf(v0.w);
    u.hh[4] = tobf(v1.x); u.hh[5] = tobf(v1.y); u.hh[6] = tobf(v1.z); u.hh[7] = tobf(v1.w);
    af[kb] = u.s;
  }
}

// ---------------- gts = relu(gt_feat @ gt_w^T + gt_b), bf16 MFMA ----------------
__global__ __launch_bounds__(256) void gts_kernel(
    const float* __restrict__ gf, const float* __restrict__ gw,
    const float* __restrict__ gb, float* __restrict__ out) {
  __shared__ __align__(16) bf As[64][LDK];
  __shared__ __align__(16) bf Bs[64][LDK];
  const int m0 = blockIdx.x * 64, n0 = blockIdx.y * 64;
  const int tid = threadIdx.x, lane = tid & 63, w = tid >> 6;
  const int m = lane & 15, quad = lane >> 4;
  f32x4 acc[4] = {{0.f,0.f,0.f,0.f},{0.f,0.f,0.f,0.f},{0.f,0.f,0.f,0.f},{0.f,0.f,0.f,0.f}};
  for (int k0 = 0; k0 < 256; k0 += 64) {
    __syncthreads();
    stage_tile(gf, m0, k0, 256, As, tid);
    stage_tile(gw, n0, k0, 256, Bs, tid);
    __syncthreads();
    #pragma unroll
    for (int kb = 0; kb < 2; ++kb) {
      short8 a = *(const short8*)&As[w * 16 + m][kb * 32 + quad * 8];
      #pragma unroll
      for (int nt = 0; nt < 4; ++nt) {
        short8 bb = *(const short8*)&Bs[nt * 16 + m][kb * 32 + quad * 8];
        acc[nt] = __builtin_amdgcn_mfma_f32_16x16x32_bf16(a, bb, acc[nt], 0, 0, 0);
      }
    }
  }
  #pragma unroll
  for (int nt = 0; nt < 4; ++nt)
    #pragma unroll
    for (int r = 0; r < 4; ++r) {
      int row = m0 + w * 16 + quad * 4 + r, col = n0 + nt * 16 + m;
      out[(size_t)row * 256 + col] = fmaxf(acc[nt][r] + gb[col], 0.f);
    }
}

// ---------------- grouped 1x1 conv + relu (fp32), dual write w/ diag seed ----------------
// out = relu(conv); out2 = relu(conv) * (seedbase + 0.25*[smask==0])
__global__ __launch_bounds__(256) void conv_kernel(
    const float* __restrict__ x, const float* __restrict__ w,
    const float* __restrict__ bias, const int* __restrict__ smask,
    float seedbase, float* __restrict__ out, float* __restrict__ out2) {
  __shared__ float Xs[64][65];
  __shared__ float Wsm[64][65];
  const int m0 = blockIdx.x * 64, g = blockIdx.y;
  const int tid = threadIdx.x, tx = tid & 15, ty = tid >> 4;
  #pragma unroll
  for (int l = 0; l < 16; ++l) {
    int idx = tid + l * 256; int r = idx >> 6, c = idx & 63;
    Xs[r][c] = x[(size_t)(m0 + r) * CH + g * DK + c];
    Wsm[r][c] = w[g * DK * DK + r * DK + c];
  }
  __syncthreads();
  float acc[4][4] = {};
  #pragma unroll 8
  for (int k = 0; k < DK; ++k) {
    float av[4], bv[4];
    #pragma unroll
    for (int i = 0; i < 4; ++i) av[i] = Xs[ty * 4 + i][k];
    #pragma unroll
    for (int j = 0; j < 4; ++j) bv[j] = Wsm[tx * 4 + j][k];
    #pragma unroll
    for (int i = 0; i < 4; ++i)
      #pragma unroll
      for (int j = 0; j < 4; ++j) acc[i][j] += av[i] * bv[j];
  }
  #pragma unroll
  for (int i = 0; i < 4; ++i) {
    int row = m0 + ty * 4 + i;
    float seed = seedbase + ((smask[row] == 0) ? 0.25f : 0.f);
    #pragma unroll
    for (int j = 0; j < 4; ++j) {
      int o = g * DK + tx * 4 + j;
      size_t idx = (size_t)row * CH + o;
      float v = fmaxf(acc[i][j] + bias[o], 0.f);
      out[idx] = v;
      out2[idx] = v * seed;
    }
  }
}

// ---------------- per-node per-head reciprocal L2 norms ----------------
__global__ void norms_kernel(const float* __restrict__ x, float* __restrict__ rn) {
  int bn = blockIdx.x;
  int t = threadIdx.x;
  float v = x[(size_t)bn * CH + t];
  float s = v * v;
  #pragma unroll
  for (int off = 32; off; off >>= 1) s += __shfl_down(s, off, 64);
  if ((t & 63) == 0) rn[bn * HEADS + (t >> 6)] = 1.0f / fmaxf(sqrtf(s), 1e-4f);
}

// top-4 insert, jax-stable tie-break (higher value first; equal value -> lower index)
__device__ inline void ins4(float v, int id, float tv[4], int tj[4]) {
  if (v < tv[3] || (v == tv[3] && id > tj[3])) return;
  tv[3] = v; tj[3] = id;
  #pragma unroll
  for (int k = 3; k > 0; --k) {
    bool sw = (tv[k] > tv[k - 1]) || (tv[k] == tv[k - 1] && tj[k] < tj[k - 1]);
    if (sw) {
      float fv = tv[k]; tv[k] = tv[k - 1]; tv[k - 1] = fv;
      int ti = tj[k]; tj[k] = tj[k - 1]; tj[k - 1] = ti;
    }
  }
}

// ---------------- per-row top-4 within a 128-col j-chunk (bf16 MFMA) ----------------
// Ranking: v = relu(dot * rnj) -- same order & zero-ties as relu(dot/(ni*nj)).
__global__ __launch_bounds__(256) void topk_part_kernel(
    const float* __restrict__ x, const float* __restrict__ rn,
    float* __restrict__ candV, int* __restrict__ candI) {
  __shared__ __align__(16) float cV[64][65];     // overlaid: Xj tile during j-loop
  __shared__ unsigned short cI[64][66];
  bf (*Xj)[LDK] = (bf(*)[LDK])cV;                // 9216 B <= 16640 B, safe overlay
  const int b = blockIdx.z, h = blockIdx.y;
  const int it = blockIdx.x >> 3, jc = blockIdx.x & 7;
  const int i0 = it * 64;
  const int tid = threadIdx.x, lane = tid & 63, w = tid >> 6;
  const int m = lane & 15, quad = lane >> 4;

  short8 afrag[2];
  load_afrag(&x[((size_t)b * NUM + i0 + w * 16 + m) * CH + h * DK], quad, afrag);

  float tv[4][4]; int tj[4][4];
  #pragma unroll
  for (int r = 0; r < 4; ++r)
    #pragma unroll
    for (int q = 0; q < 4; ++q) { tv[r][q] = -1.f; tj[r][q] = 0xffff; }

  for (int jt = 0; jt < 2; ++jt) {
    int j0 = jc * 128 + jt * 64;
    __syncthreads();
    stage_tile(x, (size_t)b * NUM + j0, h * DK, CH, Xj, tid);
    __syncthreads();
    #pragma unroll
    for (int nt = 0; nt < 4; ++nt) {
      f32x4 acc = {0.f, 0.f, 0.f, 0.f};
      #pragma unroll
      for (int kb = 0; kb < 2; ++kb) {
        short8 bb = *(const short8*)&Xj[nt * 16 + m][kb * 32 + quad * 8];
        acc = __builtin_amdgcn_mfma_f32_16x16x32_bf16(afrag[kb], bb, acc, 0, 0, 0);
      }
      int j = j0 + nt * 16 + m;
      float rnj = rn[((size_t)b * NUM + j) * HEADS + h];
      #pragma unroll
      for (int r = 0; r < 4; ++r) {
        float v = fmaxf(acc[r] * rnj, 0.f);
        ins4(v, j, tv[r], tj[r]);
      }
    }
  }
  __syncthreads();  // Xj dead; reuse memory as cV/cI
  #pragma unroll
  for (int r = 0; r < 4; ++r)
    #pragma unroll
    for (int q = 0; q < 4; ++q) {
      cV[w * 16 + quad * 4 + r][m * 4 + q] = tv[r][q];
      cI[w * 16 + quad * 4 + r][m * 4 + q] = (unsigned short)tj[r][q];
    }
  __syncthreads();
  if (tid < 64) {
    float fv[4] = {-1.f, -1.f, -1.f, -1.f};
    int fi[4] = {0x7fffffff, 0x7fffffff, 0x7fffffff, 0x7fffffff};
    for (int q = 0; q < 64; ++q) ins4(cV[tid][q], (int)cI[tid][q], fv, fi);
    size_t base = (size_t)((((b * HEADS + h) * 16 + it) * NJC + jc) * 64 + tid) * 4;
    #pragma unroll
    for (int q = 0; q < 4; ++q) { candV[base + q] = fv[q]; candI[base + q] = fi[q]; }
  }
}

// ---------------- merge NJC chunk candidates per row -> union into vec ----------------
__global__ __launch_bounds__(256) void topk_merge_kernel(
    const float* __restrict__ candV, const int* __restrict__ candI,
    float* __restrict__ vec) {
  int t = blockIdx.x * 256 + threadIdx.x;   // t = bhit*64 + rl
  int bhit = t >> 6, rl = t & 63;
  float fv[4] = {-1.f, -1.f, -1.f, -1.f};
  int fi[4] = {0x7fffffff, 0x7fffffff, 0x7fffffff, 0x7fffffff};
  #pragma unroll
  for (int jc = 0; jc < NJC; ++jc) {
    size_t base = (size_t)(((bhit) * NJC + jc) * 64 + rl) * 4;
    #pragma unroll
    for (int q = 0; q < 4; ++q) ins4(candV[base + q], candI[base + q], fv, fi);
  }
  #pragma unroll
  for (int q = 0; q < 4; ++q) vec[fi[q]] = 1.0f;  // benign race, all write 1
}

// ---------------- masked attention apply (bf16 MFMA scores + PV), j-chunked ----------------
// Ws[i][j] = pkbit(i,j) * relu(cos_ij)*0.25 ; PV uses vec-masked conv^T tile.
// Diagonal f_mask term is pre-seeded into `out` by conv_kernel.
// Per-wave Ws stripe: scores->PV needs no barrier (same-wave LDS ordering).
__global__ __launch_bounds__(256) void apply_kernel(
    const float* __restrict__ x, const float* __restrict__ conv,
    float* __restrict__ out, const float* __restrict__ rn,
    const float* __restrict__ vec, const u64* __restrict__ pk) {
  __shared__ __align__(16) bf Xj[64][LDK];
  __shared__ __align__(16) bf Cv[64][LDK];
  __shared__ __align__(16) bf Ws[64][LDK];
  const int b = blockIdx.z, h = blockIdx.y;
  const int it = blockIdx.x >> 3, jc = blockIdx.x & 7;
  const int i0 = it * 64;
  const int tid = threadIdx.x, lane = tid & 63, w = tid >> 6;
  const int m = lane & 15, quad = lane >> 4;

  short8 afrag[2];
  load_afrag(&x[((size_t)b * NUM + i0 + w * 16 + m) * CH + h * DK], quad, afrag);

  float rni4[4];
  #pragma unroll
  for (int r = 0; r < 4; ++r) {
    int row = i0 + w * 16 + quad * 4 + r;
    rni4[r] = 0.25f * rn[((size_t)b * NUM + row) * HEADS + h];
  }
  f32x4 om[4] = {{0.f,0.f,0.f,0.f},{0.f,0.f,0.f,0.f},{0.f,0.f,0.f,0.f},{0.f,0.f,0.f,0.f}};

  for (int jt = 0; jt < 2; ++jt) {
    int j0 = jc * 128 + jt * 64;
    __syncthreads();   // protect Xj/Cv from previous iteration's readers
    stage_tile(x, (size_t)b * NUM + j0, h * DK, CH, Xj, tid);
    {  // vec-masked conv^T tile
      int jr = tid >> 4, c4 = tid & 15;
      #pragma unroll
      for (int itt = 0; itt < 4; ++itt) {
        int j = jr + itt * 16;
        float vm = vec[j0 + j];
        const float4 v = *(const float4*)&conv[((size_t)b * NUM + j0 + j) * CH + h * DK + c4 * 4];
        Cv[c4 * 4 + 0][j] = tobf(v.x * vm);
        Cv[c4 * 4 + 1][j] = tobf(v.y * vm);
        Cv[c4 * 4 + 2][j] = tobf(v.z * vm);
        Cv[c4 * 4 + 3][j] = tobf(v.w * vm);
      }
    }
    u64 wr[4];
    #pragma unroll
    for (int r = 0; r < 4; ++r)
      wr[r] = pk[((size_t)b * NUM + i0 + w * 16 + quad * 4 + r) * 16 + (j0 >> 6)];
    __syncthreads();
    // scores -> masked weights -> Ws (own wave's 16-row stripe only)
    #pragma unroll
    for (int nt = 0; nt < 4; ++nt) {
      f32x4 acc = {0.f, 0.f, 0.f, 0.f};
      #pragma unroll
      for (int kb = 0; kb < 2; ++kb) {
        short8 bb = *(const short8*)&Xj[nt * 16 + m][kb * 32 + quad * 8];
        acc = __builtin_amdgcn_mfma_f32_16x16x32_bf16(afrag[kb], bb, acc, 0, 0, 0);
      }
      float rnj = rn[((size_t)b * NUM + j0 + nt * 16 + m) * HEADS + h];
      #pragma unroll
      for (int r = 0; r < 4; ++r) {
        float a = fmaxf(acc[r] * rni4[r] * rnj, 0.f);
        bool bit = (wr[r] >> (nt * 16 + m)) & 1ull;
        Ws[w * 16 + quad * 4 + r][nt * 16 + m] = tobf(bit ? a : 0.f);
      }
    }
    // PV: same-wave Ws stripe + Cv (stable until next loop-top barrier)
    #pragma unroll
    for (int kb = 0; kb < 2; ++kb) {
      short8 a = *(const short8*)&Ws[w * 16 + m][kb * 32 + quad * 8];
      #pragma unroll
      for (int ct = 0; ct < 4; ++ct) {
        short8 bb = *(const short8*)&Cv[ct * 16 + m][kb * 32 + quad * 8];
        om[ct] = __builtin_amdgcn_mfma_f32_16x16x32_bf16(a, bb, om[ct], 0, 0, 0);
      }
    }
  }
  #pragma unroll
  for (int ct = 0; ct < 4; ++ct)
    #pragma unroll
    for (int r = 0; r < 4; ++r) {
      size_t idx = ((size_t)b * NUM + i0 + w * 16 + quad * 4 + r) * CH + h * DK + ct * 16 + m;
      atomicAdd(&out[idx], om[ct][r]);
    }
}

// ---------------- LayerNorm + final outputs (in-place on d_out regions) ----------------
__global__ __launch_bounds__(256) void final_kernel(
    float* __restrict__ ybnf, float* __restrict__ out0,
    const float* __restrict__ lnw, const float* __restrict__ lnb) {
  __shared__ float r1[4];
  __shared__ float r2[4];
  int bn = blockIdx.x;
  int c = threadIdx.x;
  size_t idx = (size_t)bn * CH + c;
  float y = ybnf[idx];
  float x2v = out0[idx];
  float s = y;
  #pragma unroll
  for (int off = 32; off; off >>= 1) s += __shfl_down(s, off, 64);
  int wave = c >> 6, lane = c & 63;
  if (lane == 0) r1[wave] = s;
  __syncthreads();
  float mu = (r1[0] + r1[1] + r1[2] + r1[3]) * (1.f / 256.f);
  float d = y - mu;
  float s2 = d * d;
  #pragma unroll
  for (int off = 32; off; off >>= 1) s2 += __shfl_down(s2, off, 64);
  if (lane == 0) r2[wave] = s2;
  __syncthreads();
  float var = (r2[0] + r2[1] + r2[2] + r2[3]) * (1.f / 256.f);
  float nf = d * rsqrtf(var + 1e-6f) * lnw[c] + lnb[c];
  ybnf[idx] = nf;
  out0[idx] = x2v + nf;
}

extern "C" void kernel_launch(void* const* d_in, const int* in_sizes, int n_in,
                              void* d_out, int out_size, void* d_ws, size_t ws_size,
                              hipStream_t stream) {
  const float* input = (const float*)d_in[0];
  const int* mroi = (const int*)d_in[1];
  const int* smask = (const int*)d_in[2];
  const float* gt_feat = (const float*)d_in[3];
  const float* w1 = (const float*)d_in[4];
  const float* b1 = (const float*)d_in[5];
  const float* w2 = (const float*)d_in[6];
  const float* b2 = (const float*)d_in[7];
  const float* gt_w = (const float*)d_in[8];
  const float* gt_b = (const float*)d_in[9];
  const float* lnw = (const float*)d_in[10];
  const float* lnb = (const float*)d_in[11];

  const size_t SEG = (size_t)B_ * NUM * CH;  // 1048576 elements
  float* out0 = (float*)d_out;     // finally: out2^T + node_feat ; interim: X2 (conv2)
  float* gts = out0 + SEG;         // gts output (final from the start)
  float* nfreg = out0 + 2 * SEG;   // finally: node_feat ; interim: X1 then Yb

  // ws: F1 4MB | RN 64KB | VEC 8KB | candV 2MB | candI 2MB | PK 512KB ~= 8.6 MB
  float* F1 = (float*)d_ws;
  float* RN = F1 + SEG;
  float* VEC1 = RN + (size_t)B_ * NUM * HEADS;
  float* VEC2 = VEC1 + NUM;
  float* candV = VEC2 + NUM;
  const size_t NCAND = (size_t)B_ * HEADS * 16 * NJC * 64 * 4;
  int* candI = (int*)(candV + NCAND);
  u64* PK = (u64*)(candI + NCAND);

  float* X1 = nfreg;  // conv1 output (F1 seeded = X1*(1+0.25*[sm==0]))
  float* X2 = out0;   // conv2 output lives in out0 region until final_kernel
  float* Yb = nfreg;  // o2m accumulator (seeded = 0.25*[sm==0]*X2, overwrites dead X1)

  zero_vec_kernel<<<4, 256, 0, stream>>>(VEC1, VEC2);
  pack_kernel<<<1024, 256, 0, stream>>>(mroi, smask, PK);
  gts_kernel<<<dim3(64, 4), 256, 0, stream>>>(gt_feat, gt_w, gt_b, gts);

  // stage 1
  conv_kernel<<<dim3(64, 4), 256, 0, stream>>>(input, w1, b1, smask, 1.0f, X1, F1);
  norms_kernel<<<4096, 256, 0, stream>>>(input, RN);
  topk_part_kernel<<<dim3(16 * NJC, HEADS, B_), 256, 0, stream>>>(input, RN, candV, candI);
  topk_merge_kernel<<<64, 256, 0, stream>>>(candV, candI, VEC1);
  apply_kernel<<<dim3(16 * NJC, HEADS, B_), 256, 0, stream>>>(
      input, X1, F1, RN, VEC1, PK);

  // stage 2
  conv_kernel<<<dim3(64, 4), 256, 0, stream>>>(F1, w2, b2, smask, 0.0f, X2, Yb);
  norms_kernel<<<4096, 256, 0, stream>>>(F1, RN);
  topk_part_kernel<<<dim3(16 * NJC, HEADS, B_), 256, 0, stream>>>(F1, RN, candV, candI);
  topk_merge_kernel<<<64, 256, 0, stream>>>(candV, candI, VEC2);
  apply_kernel<<<dim3(16 * NJC, HEADS, B_), 256, 0, stream>>>(
      F1, X2, Yb, RN, VEC2, PK);

  final_kernel<<<4096, 256, 0, stream>>>(Yb, X2, lnw, lnb);
}

// Round 10
// 285.520 us; speedup vs baseline: 1.1095x; 1.0873x over previous
//
#include <hip/hip_runtime.h>
#include <hip/hip_bf16.h>

#define B_    4
#define NUM   1024
#define CH    256
#define HEADS 4
#define DK    64
#define LDK   72   // padded LDS row stride in bf16 elements (2-way bank alias = free)
#define NJC   4    // j-chunks per (b,h,i-tile); chunk = 256 cols = 4 j-tiles

typedef __hip_bfloat16 bf;
typedef __attribute__((ext_vector_type(8))) short short8;
typedef __attribute__((ext_vector_type(4))) float f32x4;
typedef unsigned long long u64;

__device__ inline bf tobf(float v) { return __float2bfloat16(v); }

// ---------------- pack (mroi && smask_j) into bit-words + zero vec masks ----------------
__global__ __launch_bounds__(256) void pack_kernel(
    const int* __restrict__ mroi, const int* __restrict__ smask,
    u64* __restrict__ pk, float* __restrict__ v1, float* __restrict__ v2) {
  if (blockIdx.x < 4) {
    int i = blockIdx.x * 256 + threadIdx.x;
    v1[i] = 0.f; v2[i] = 0.f;
  }
  int row = blockIdx.x * 4 + (threadIdx.x >> 6);
  int lane = threadIdx.x & 63;
  int b = row >> 10;
  const int* mr = &mroi[(size_t)row * NUM];
  const int* sm = &smask[b * NUM];
  #pragma unroll
  for (int w = 0; w < 16; ++w) {
    int j = w * 64 + lane;
    u64 word = __ballot((mr[j] != 0) && (sm[j] != 0));
    if (lane == 0) pk[(size_t)row * 16 + w] = word;
  }
}

// stage a 64x64 fp32 global tile -> bf16 LDS tile [64][LDK]
__device__ inline void stage_tile(const float* __restrict__ src, size_t row0,
                                  int col0, int rowstride, bf (*dst)[LDK], int tid) {
  int r = tid >> 4, c4 = (tid & 15) * 4;
  #pragma unroll
  for (int it = 0; it < 4; ++it) {
    int row = r + it * 16;
    const float4 v = *(const float4*)&src[(row0 + row) * (size_t)rowstride + col0 + c4];
    union { bf h4[4]; short4 s4; } u;
    u.h4[0] = tobf(v.x); u.h4[1] = tobf(v.y); u.h4[2] = tobf(v.z); u.h4[3] = tobf(v.w);
    *(short4*)&dst[row][c4] = u.s4;
  }
}

// load this lane's A-fragments (2 k-blocks) straight from global into registers
__device__ inline void load_afrag(const float* __restrict__ arow, int quad, short8 af[2]) {
  #pragma unroll
  for (int kb = 0; kb < 2; ++kb) {
    const float4 v0 = *(const float4*)&arow[kb * 32 + quad * 8];
    const float4 v1 = *(const float4*)&arow[kb * 32 + quad * 8 + 4];
    union { bf hh[8]; short8 s; } u;
    u.hh[0] = tobf(v0.x); u.hh[1] = tobf(v0.y); u.hh[2] = tobf(v0.z); u.hh[3] = tobf(v0.w);
    u.hh[4] = tobf(v1.x); u.hh[5] = tobf(v1.y); u.hh[6] = tobf(v1.z); u.hh[7] = tobf(v1.w);
    af[kb] = u.s;
  }
}

// ---------------- gts = relu(gt_feat @ gt_w^T + gt_b), bf16 MFMA ----------------
__global__ __launch_bounds__(256) void gts_kernel(
    const float* __restrict__ gf, const float* __restrict__ gw,
    const float* __restrict__ gb, float* __restrict__ out) {
  __shared__ __align__(16) bf As[64][LDK];
  __shared__ __align__(16) bf Bs[64][LDK];
  const int m0 = blockIdx.x * 64, n0 = blockIdx.y * 64;
  const int tid = threadIdx.x, lane = tid & 63, w = tid >> 6;
  const int m = lane & 15, quad = lane >> 4;
  f32x4 acc[4] = {{0.f,0.f,0.f,0.f},{0.f,0.f,0.f,0.f},{0.f,0.f,0.f,0.f},{0.f,0.f,0.f,0.f}};
  for (int k0 = 0; k0 < 256; k0 += 64) {
    __syncthreads();
    stage_tile(gf, m0, k0, 256, As, tid);
    stage_tile(gw, n0, k0, 256, Bs, tid);
    __syncthreads();
    #pragma unroll
    for (int kb = 0; kb < 2; ++kb) {
      short8 a = *(const short8*)&As[w * 16 + m][kb * 32 + quad * 8];
      #pragma unroll
      for (int nt = 0; nt < 4; ++nt) {
        short8 bb = *(const short8*)&Bs[nt * 16 + m][kb * 32 + quad * 8];
        acc[nt] = __builtin_amdgcn_mfma_f32_16x16x32_bf16(a, bb, acc[nt], 0, 0, 0);
      }
    }
  }
  #pragma unroll
  for (int nt = 0; nt < 4; ++nt)
    #pragma unroll
    for (int r = 0; r < 4; ++r) {
      int row = m0 + w * 16 + quad * 4 + r, col = n0 + nt * 16 + m;
      out[(size_t)row * 256 + col] = fmaxf(acc[nt][r] + gb[col], 0.f);
    }
}

// ---------------- grouped 1x1 conv + relu (fp32), dual write w/ diag seed ----------------
// Also emits rn (reciprocal per-head L2 norm of the INPUT slice): head == group.
// out = relu(conv); out2 = relu(conv) * (seedbase + 0.25*[smask==0])
__global__ __launch_bounds__(256) void conv_kernel(
    const float* __restrict__ x, const float* __restrict__ w,
    const float* __restrict__ bias, const int* __restrict__ smask,
    float seedbase, float* __restrict__ out, float* __restrict__ out2,
    float* __restrict__ rn) {
  __shared__ float Xs[64][65];
  __shared__ float Wsm[64][65];
  const int m0 = blockIdx.x * 64, g = blockIdx.y;
  const int tid = threadIdx.x, tx = tid & 15, ty = tid >> 4;
  #pragma unroll
  for (int l = 0; l < 16; ++l) {
    int idx = tid + l * 256; int r = idx >> 6, c = idx & 63;
    Xs[r][c] = x[(size_t)(m0 + r) * CH + g * DK + c];
    Wsm[r][c] = w[g * DK * DK + r * DK + c];
  }
  __syncthreads();
  // fused reciprocal norms: 4 lanes per row, 16 channels each, shfl_xor reduce
  {
    int wv = tid >> 6, lane = tid & 63;
    int row = wv * 16 + (lane >> 2), part = lane & 3;
    float s = 0.f;
    #pragma unroll
    for (int k = 0; k < 16; ++k) {
      float v = Xs[row][part * 16 + k];
      s += v * v;
    }
    s += __shfl_xor(s, 1, 64);
    s += __shfl_xor(s, 2, 64);
    if (part == 0)
      rn[(size_t)(m0 + row) * HEADS + g] = 1.0f / fmaxf(sqrtf(s), 1e-4f);
  }
  float acc[4][4] = {};
  #pragma unroll 8
  for (int k = 0; k < DK; ++k) {
    float av[4], bv[4];
    #pragma unroll
    for (int i = 0; i < 4; ++i) av[i] = Xs[ty * 4 + i][k];
    #pragma unroll
    for (int j = 0; j < 4; ++j) bv[j] = Wsm[tx * 4 + j][k];
    #pragma unroll
    for (int i = 0; i < 4; ++i)
      #pragma unroll
      for (int j = 0; j < 4; ++j) acc[i][j] += av[i] * bv[j];
  }
  #pragma unroll
  for (int i = 0; i < 4; ++i) {
    int row = m0 + ty * 4 + i;
    float seed = seedbase + ((smask[row] == 0) ? 0.25f : 0.f);
    #pragma unroll
    for (int j = 0; j < 4; ++j) {
      int o = g * DK + tx * 4 + j;
      size_t idx = (size_t)row * CH + o;
      float v = fmaxf(acc[i][j] + bias[o], 0.f);
      out[idx] = v;
      out2[idx] = v * seed;
    }
  }
}

// top-4 insert, jax-stable tie-break (higher value first; equal value -> lower index)
__device__ inline void ins4(float v, int id, float tv[4], int tj[4]) {
  if (v < tv[3] || (v == tv[3] && id > tj[3])) return;
  tv[3] = v; tj[3] = id;
  #pragma unroll
  for (int k = 3; k > 0; --k) {
    bool sw = (tv[k] > tv[k - 1]) || (tv[k] == tv[k - 1] && tj[k] < tj[k - 1]);
    if (sw) {
      float fv = tv[k]; tv[k] = tv[k - 1]; tv[k - 1] = fv;
      int ti = tj[k]; tj[k] = tj[k - 1]; tj[k - 1] = ti;
    }
  }
}

// ---------------- per-row top-4 within a 256-col j-chunk (bf16 MFMA) ----------------
// Ranking: v = relu(dot * rnj) -- same order & zero-ties as relu(dot/(ni*nj)).
__global__ __launch_bounds__(256) void topk_part_kernel(
    const float* __restrict__ x, const float* __restrict__ rn,
    float* __restrict__ candV, int* __restrict__ candI) {
  __shared__ __align__(16) float cV[64][65];     // overlaid: Xj tile during j-loop
  __shared__ unsigned short cI[64][66];
  bf (*Xj)[LDK] = (bf(*)[LDK])cV;                // 9216 B <= 16640 B, safe overlay
  const int b = blockIdx.z, h = blockIdx.y;
  const int it = blockIdx.x >> 2, jc = blockIdx.x & 3;
  const int i0 = it * 64;
  const int tid = threadIdx.x, lane = tid & 63, w = tid >> 6;
  const int m = lane & 15, quad = lane >> 4;

  short8 afrag[2];
  load_afrag(&x[((size_t)b * NUM + i0 + w * 16 + m) * CH + h * DK], quad, afrag);

  float tv[4][4]; int tj[4][4];
  #pragma unroll
  for (int r = 0; r < 4; ++r)
    #pragma unroll
    for (int q = 0; q < 4; ++q) { tv[r][q] = -1.f; tj[r][q] = 0xffff; }

  for (int jt = 0; jt < 4; ++jt) {
    int j0 = jc * 256 + jt * 64;
    __syncthreads();
    stage_tile(x, (size_t)b * NUM + j0, h * DK, CH, Xj, tid);
    __syncthreads();
    #pragma unroll
    for (int nt = 0; nt < 4; ++nt) {
      f32x4 acc = {0.f, 0.f, 0.f, 0.f};
      #pragma unroll
      for (int kb = 0; kb < 2; ++kb) {
        short8 bb = *(const short8*)&Xj[nt * 16 + m][kb * 32 + quad * 8];
        acc = __builtin_amdgcn_mfma_f32_16x16x32_bf16(afrag[kb], bb, acc, 0, 0, 0);
      }
      int j = j0 + nt * 16 + m;
      float rnj = rn[((size_t)b * NUM + j) * HEADS + h];
      #pragma unroll
      for (int r = 0; r < 4; ++r) {
        float v = fmaxf(acc[r] * rnj, 0.f);
        ins4(v, j, tv[r], tj[r]);
      }
    }
  }
  __syncthreads();  // Xj dead; reuse memory as cV/cI
  #pragma unroll
  for (int r = 0; r < 4; ++r)
    #pragma unroll
    for (int q = 0; q < 4; ++q) {
      cV[w * 16 + quad * 4 + r][m * 4 + q] = tv[r][q];
      cI[w * 16 + quad * 4 + r][m * 4 + q] = (unsigned short)tj[r][q];
    }
  __syncthreads();
  if (tid < 64) {
    float fv[4] = {-1.f, -1.f, -1.f, -1.f};
    int fi[4] = {0x7fffffff, 0x7fffffff, 0x7fffffff, 0x7fffffff};
    for (int q = 0; q < 64; ++q) ins4(cV[tid][q], (int)cI[tid][q], fv, fi);
    size_t base = (size_t)((((b * HEADS + h) * 16 + it) * NJC + jc) * 64 + tid) * 4;
    #pragma unroll
    for (int q = 0; q < 4; ++q) { candV[base + q] = fv[q]; candI[base + q] = fi[q]; }
  }
}

// ---------------- merge NJC chunk candidates per row -> union into vec ----------------
__global__ __launch_bounds__(256) void topk_merge_kernel(
    const float* __restrict__ candV, const int* __restrict__ candI,
    float* __restrict__ vec) {
  int t = blockIdx.x * 256 + threadIdx.x;   // t = bhit*64 + rl
  int bhit = t >> 6, rl = t & 63;
  float fv[4] = {-1.f, -1.f, -1.f, -1.f};
  int fi[4] = {0x7fffffff, 0x7fffffff, 0x7fffffff, 0x7fffffff};
  #pragma unroll
  for (int jc = 0; jc < NJC; ++jc) {
    size_t base = (size_t)(((bhit) * NJC + jc) * 64 + rl) * 4;
    #pragma unroll
    for (int q = 0; q < 4; ++q) ins4(candV[base + q], candI[base + q], fv, fi);
  }
  #pragma unroll
  for (int q = 0; q < 4; ++q) vec[fi[q]] = 1.0f;  // benign race, all write 1
}

// ---------------- masked attention apply (bf16 MFMA scores + PV), j-chunked ----------------
// Ws[i][j] = pkbit(i,j) * relu(cos_ij)*0.25 ; PV uses vec-masked conv^T tile.
// Diagonal f_mask term is pre-seeded into `out` by conv_kernel.
// Per-wave Ws stripe: scores->PV needs no barrier (same-wave LDS ordering).
__global__ __launch_bounds__(256) void apply_kernel(
    const float* __restrict__ x, const float* __restrict__ conv,
    float* __restrict__ out, const float* __restrict__ rn,
    const float* __restrict__ vec, const u64* __restrict__ pk) {
  __shared__ __align__(16) bf Xj[64][LDK];
  __shared__ __align__(16) bf Cv[64][LDK];
  __shared__ __align__(16) bf Ws[64][LDK];
  const int b = blockIdx.z, h = blockIdx.y;
  const int it = blockIdx.x >> 2, jc = blockIdx.x & 3;
  const int i0 = it * 64;
  const int tid = threadIdx.x, lane = tid & 63, w = tid >> 6;
  const int m = lane & 15, quad = lane >> 4;

  short8 afrag[2];
  load_afrag(&x[((size_t)b * NUM + i0 + w * 16 + m) * CH + h * DK], quad, afrag);

  float rni4[4];
  #pragma unroll
  for (int r = 0; r < 4; ++r) {
    int row = i0 + w * 16 + quad * 4 + r;
    rni4[r] = 0.25f * rn[((size_t)b * NUM + row) * HEADS + h];
  }
  f32x4 om[4] = {{0.f,0.f,0.f,0.f},{0.f,0.f,0.f,0.f},{0.f,0.f,0.f,0.f},{0.f,0.f,0.f,0.f}};

  for (int jt = 0; jt < 4; ++jt) {
    int j0 = jc * 256 + jt * 64;
    __syncthreads();   // protect Xj/Cv from previous iteration's readers
    stage_tile(x, (size_t)b * NUM + j0, h * DK, CH, Xj, tid);
    {  // vec-masked conv^T tile
      int jr = tid >> 4, c4 = tid & 15;
      #pragma unroll
      for (int itt = 0; itt < 4; ++itt) {
        int j = jr + itt * 16;
        float vm = vec[j0 + j];
        const float4 v = *(const float4*)&conv[((size_t)b * NUM + j0 + j) * CH + h * DK + c4 * 4];
        Cv[c4 * 4 + 0][j] = tobf(v.x * vm);
        Cv[c4 * 4 + 1][j] = tobf(v.y * vm);
        Cv[c4 * 4 + 2][j] = tobf(v.z * vm);
        Cv[c4 * 4 + 3][j] = tobf(v.w * vm);
      }
    }
    u64 wr[4];
    #pragma unroll
    for (int r = 0; r < 4; ++r)
      wr[r] = pk[((size_t)b * NUM + i0 + w * 16 + quad * 4 + r) * 16 + (j0 >> 6)];
    __syncthreads();
    // scores -> masked weights -> Ws (own wave's 16-row stripe only)
    #pragma unroll
    for (int nt = 0; nt < 4; ++nt) {
      f32x4 acc = {0.f, 0.f, 0.f, 0.f};
      #pragma unroll
      for (int kb = 0; kb < 2; ++kb) {
        short8 bb = *(const short8*)&Xj[nt * 16 + m][kb * 32 + quad * 8];
        acc = __builtin_amdgcn_mfma_f32_16x16x32_bf16(afrag[kb], bb, acc, 0, 0, 0);
      }
      float rnj = rn[((size_t)b * NUM + j0 + nt * 16 + m) * HEADS + h];
      #pragma unroll
      for (int r = 0; r < 4; ++r) {
        float a = fmaxf(acc[r] * rni4[r] * rnj, 0.f);
        bool bit = (wr[r] >> (nt * 16 + m)) & 1ull;
        Ws[w * 16 + quad * 4 + r][nt * 16 + m] = tobf(bit ? a : 0.f);
      }
    }
    // PV: same-wave Ws stripe + Cv (stable until next loop-top barrier)
    #pragma unroll
    for (int kb = 0; kb < 2; ++kb) {
      short8 a = *(const short8*)&Ws[w * 16 + m][kb * 32 + quad * 8];
      #pragma unroll
      for (int ct = 0; ct < 4; ++ct) {
        short8 bb = *(const short8*)&Cv[ct * 16 + m][kb * 32 + quad * 8];
        om[ct] = __builtin_amdgcn_mfma_f32_16x16x32_bf16(a, bb, om[ct], 0, 0, 0);
      }
    }
  }
  #pragma unroll
  for (int ct = 0; ct < 4; ++ct)
    #pragma unroll
    for (int r = 0; r < 4; ++r) {
      size_t idx = ((size_t)b * NUM + i0 + w * 16 + quad * 4 + r) * CH + h * DK + ct * 16 + m;
      atomicAdd(&out[idx], om[ct][r]);
    }
}

// ---------------- LayerNorm + final outputs (in-place on d_out regions) ----------------
__global__ __launch_bounds__(256) void final_kernel(
    float* __restrict__ ybnf, float* __restrict__ out0,
    const float* __restrict__ lnw, const float* __restrict__ lnb) {
  __shared__ float r1[4];
  __shared__ float r2[4];
  int bn = blockIdx.x;
  int c = threadIdx.x;
  size_t idx = (size_t)bn * CH + c;
  float y = ybnf[idx];
  float x2v = out0[idx];
  float s = y;
  #pragma unroll
  for (int off = 32; off; off >>= 1) s += __shfl_down(s, off, 64);
  int wave = c >> 6, lane = c & 63;
  if (lane == 0) r1[wave] = s;
  __syncthreads();
  float mu = (r1[0] + r1[1] + r1[2] + r1[3]) * (1.f / 256.f);
  float d = y - mu;
  float s2 = d * d;
  #pragma unroll
  for (int off = 32; off; off >>= 1) s2 += __shfl_down(s2, off, 64);
  if (lane == 0) r2[wave] = s2;
  __syncthreads();
  float var = (r2[0] + r2[1] + r2[2] + r2[3]) * (1.f / 256.f);
  float nf = d * rsqrtf(var + 1e-6f) * lnw[c] + lnb[c];
  ybnf[idx] = nf;
  out0[idx] = x2v + nf;
}

extern "C" void kernel_launch(void* const* d_in, const int* in_sizes, int n_in,
                              void* d_out, int out_size, void* d_ws, size_t ws_size,
                              hipStream_t stream) {
  const float* input = (const float*)d_in[0];
  const int* mroi = (const int*)d_in[1];
  const int* smask = (const int*)d_in[2];
  const float* gt_feat = (const float*)d_in[3];
  const float* w1 = (const float*)d_in[4];
  const float* b1 = (const float*)d_in[5];
  const float* w2 = (const float*)d_in[6];
  const float* b2 = (const float*)d_in[7];
  const float* gt_w = (const float*)d_in[8];
  const float* gt_b = (const float*)d_in[9];
  const float* lnw = (const float*)d_in[10];
  const float* lnb = (const float*)d_in[11];

  const size_t SEG = (size_t)B_ * NUM * CH;  // 1048576 elements
  float* out0 = (float*)d_out;     // finally: out2^T + node_feat ; interim: X2 (conv2)
  float* gts = out0 + SEG;         // gts output (final from the start)
  float* nfreg = out0 + 2 * SEG;   // finally: node_feat ; interim: X1 then Yb

  // ws: F1 4MB | RN 64KB | VEC 8KB | candV 1MB | candI 1MB | PK 512KB ~= 6.6 MB
  float* F1 = (float*)d_ws;
  float* RN = F1 + SEG;
  float* VEC1 = RN + (size_t)B_ * NUM * HEADS;
  float* VEC2 = VEC1 + NUM;
  float* candV = VEC2 + NUM;
  const size_t NCAND = (size_t)B_ * HEADS * 16 * NJC * 64 * 4;
  int* candI = (int*)(candV + NCAND);
  u64* PK = (u64*)(candI + NCAND);

  float* X1 = nfreg;  // conv1 output (F1 seeded = X1*(1+0.25*[sm==0]))
  float* X2 = out0;   // conv2 output lives in out0 region until final_kernel
  float* Yb = nfreg;  // o2m accumulator (seeded = 0.25*[sm==0]*X2, overwrites dead X1)

  pack_kernel<<<1024, 256, 0, stream>>>(mroi, smask, PK, VEC1, VEC2);
  gts_kernel<<<dim3(64, 4), 256, 0, stream>>>(gt_feat, gt_w, gt_b, gts);

  // stage 1
  conv_kernel<<<dim3(64, 4), 256, 0, stream>>>(input, w1, b1, smask, 1.0f, X1, F1, RN);
  topk_part_kernel<<<dim3(16 * NJC, HEADS, B_), 256, 0, stream>>>(input, RN, candV, candI);
  topk_merge_kernel<<<64, 256, 0, stream>>>(candV, candI, VEC1);
  apply_kernel<<<dim3(16 * NJC, HEADS, B_), 256, 0, stream>>>(
      input, X1, F1, RN, VEC1, PK);

  // stage 2
  conv_kernel<<<dim3(64, 4), 256, 0, stream>>>(F1, w2, b2, smask, 0.0f, X2, Yb, RN);
  topk_part_kernel<<<dim3(16 * NJC, HEADS, B_), 256, 0, stream>>>(F1, RN, candV, candI);
  topk_merge_kernel<<<64, 256, 0, stream>>>(candV, candI, VEC2);
  apply_kernel<<<dim3(16 * NJC, HEADS, B_), 256, 0, stream>>>(
      F1, X2, Yb, RN, VEC2, PK);

  final_kernel<<<4096, 256, 0, stream>>>(Yb, X2, lnw, lnb);
}

// Round 12
// 283.348 us; speedup vs baseline: 1.1180x; 1.0077x over previous
//
#include <hip/hip_runtime.h>
#include <hip/hip_bf16.h>

#define B_    4
#define NUM   1024
#define CH    256
#define HEADS 4
#define DK    64
#define LDK   72   // padded LDS row stride in bf16 elements (2-way bank alias = free)
#define NJC   4    // j-chunks per (b,h,i-tile); chunk = 256 cols = 4 j-tiles

typedef __hip_bfloat16 bf;
typedef __attribute__((ext_vector_type(8))) short short8;
typedef __attribute__((ext_vector_type(4))) float f32x4;
typedef unsigned long long u64;

__device__ inline bf tobf(float v) { return __float2bfloat16(v); }

// ---------------- pack (mroi && smask_j) into bit-words + zero vec masks ----------------
__global__ __launch_bounds__(256) void pack_kernel(
    const int* __restrict__ mroi, const int* __restrict__ smask,
    u64* __restrict__ pk, float* __restrict__ v1, float* __restrict__ v2) {
  if (blockIdx.x < 4) {
    int i = blockIdx.x * 256 + threadIdx.x;
    v1[i] = 0.f; v2[i] = 0.f;
  }
  int row = blockIdx.x * 4 + (threadIdx.x >> 6);
  int lane = threadIdx.x & 63;
  int b = row >> 10;
  const int* mr = &mroi[(size_t)row * NUM];
  const int* sm = &smask[b * NUM];
  #pragma unroll
  for (int w = 0; w < 16; ++w) {
    int j = w * 64 + lane;
    u64 word = __ballot((mr[j] != 0) && (sm[j] != 0));
    if (lane == 0) pk[(size_t)row * 16 + w] = word;
  }
}

// stage a 64x64 fp32 global tile -> bf16 LDS tile [64][LDK]
__device__ inline void stage_tile(const float* __restrict__ src, size_t row0,
                                  int col0, int rowstride, bf (*dst)[LDK], int tid) {
  int r = tid >> 4, c4 = (tid & 15) * 4;
  #pragma unroll
  for (int it = 0; it < 4; ++it) {
    int row = r + it * 16;
    const float4 v = *(const float4*)&src[(row0 + row) * (size_t)rowstride + col0 + c4];
    union { bf h4[4]; short4 s4; } u;
    u.h4[0] = tobf(v.x); u.h4[1] = tobf(v.y); u.h4[2] = tobf(v.z); u.h4[3] = tobf(v.w);
    *(short4*)&dst[row][c4] = u.s4;
  }
}

// load this lane's A-fragments (2 k-blocks) straight from global into registers
__device__ inline void load_afrag(const float* __restrict__ arow, int quad, short8 af[2]) {
  #pragma unroll
  for (int kb = 0; kb < 2; ++kb) {
    const float4 v0 = *(const float4*)&arow[kb * 32 + quad * 8];
    const float4 v1 = *(const float4*)&arow[kb * 32 + quad * 8 + 4];
    union { bf hh[8]; short8 s; } u;
    u.hh[0] = tobf(v0.x); u.hh[1] = tobf(v0.y); u.hh[2] = tobf(v0.z); u.hh[3] = tobf(v0.w);
    u.hh[4] = tobf(v1.x); u.hh[5] = tobf(v1.y); u.hh[6] = tobf(v1.z); u.hh[7] = tobf(v1.w);
    af[kb] = u.s;
  }
}

// ---------------- gts = relu(gt_feat @ gt_w^T + gt_b), bf16 MFMA ----------------
__global__ __launch_bounds__(256) void gts_kernel(
    const float* __restrict__ gf, const float* __restrict__ gw,
    const float* __restrict__ gb, float* __restrict__ out) {
  __shared__ __align__(16) bf As[64][LDK];
  __shared__ __align__(16) bf Bs[64][LDK];
  const int m0 = blockIdx.x * 64, n0 = blockIdx.y * 64;
  const int tid = threadIdx.x, lane = tid & 63, w = tid >> 6;
  const int m = lane & 15, quad = lane >> 4;
  f32x4 acc[4] = {{0.f,0.f,0.f,0.f},{0.f,0.f,0.f,0.f},{0.f,0.f,0.f,0.f},{0.f,0.f,0.f,0.f}};
  for (int k0 = 0; k0 < 256; k0 += 64) {
    __syncthreads();
    stage_tile(gf, m0, k0, 256, As, tid);
    stage_tile(gw, n0, k0, 256, Bs, tid);
    __syncthreads();
    #pragma unroll
    for (int kb = 0; kb < 2; ++kb) {
      short8 a = *(const short8*)&As[w * 16 + m][kb * 32 + quad * 8];
      #pragma unroll
      for (int nt = 0; nt < 4; ++nt) {
        short8 bb = *(const short8*)&Bs[nt * 16 + m][kb * 32 + quad * 8];
        acc[nt] = __builtin_amdgcn_mfma_f32_16x16x32_bf16(a, bb, acc[nt], 0, 0, 0);
      }
    }
  }
  #pragma unroll
  for (int nt = 0; nt < 4; ++nt)
    #pragma unroll
    for (int r = 0; r < 4; ++r) {
      int row = m0 + w * 16 + quad * 4 + r, col = n0 + nt * 16 + m;
      out[(size_t)row * 256 + col] = fmaxf(acc[nt][r] + gb[col], 0.f);
    }
}

// ---------------- grouped 1x1 conv + relu (fp32), dual write w/ diag seed ----------------
// Also emits rn (reciprocal per-head L2 norm of the INPUT slice): head == group.
// out = relu(conv); out2 = relu(conv) * (seedbase + 0.25*[smask==0])
__global__ __launch_bounds__(256) void conv_kernel(
    const float* __restrict__ x, const float* __restrict__ w,
    const float* __restrict__ bias, const int* __restrict__ smask,
    float seedbase, float* __restrict__ out, float* __restrict__ out2,
    float* __restrict__ rn) {
  __shared__ float Xs[64][65];
  __shared__ float Wsm[64][65];
  const int m0 = blockIdx.x * 64, g = blockIdx.y;
  const int tid = threadIdx.x, tx = tid & 15, ty = tid >> 4;
  #pragma unroll
  for (int l = 0; l < 16; ++l) {
    int idx = tid + l * 256; int r = idx >> 6, c = idx & 63;
    Xs[r][c] = x[(size_t)(m0 + r) * CH + g * DK + c];
    Wsm[r][c] = w[g * DK * DK + r * DK + c];
  }
  __syncthreads();
  // fused reciprocal norms: 4 lanes per row, 16 channels each, shfl_xor reduce
  {
    int wv = tid >> 6, lane = tid & 63;
    int row = wv * 16 + (lane >> 2), part = lane & 3;
    float s = 0.f;
    #pragma unroll
    for (int k = 0; k < 16; ++k) {
      float v = Xs[row][part * 16 + k];
      s += v * v;
    }
    s += __shfl_xor(s, 1, 64);
    s += __shfl_xor(s, 2, 64);
    if (part == 0)
      rn[(size_t)(m0 + row) * HEADS + g] = 1.0f / fmaxf(sqrtf(s), 1e-4f);
  }
  float acc[4][4] = {};
  #pragma unroll 8
  for (int k = 0; k < DK; ++k) {
    float av[4], bv[4];
    #pragma unroll
    for (int i = 0; i < 4; ++i) av[i] = Xs[ty * 4 + i][k];
    #pragma unroll
    for (int j = 0; j < 4; ++j) bv[j] = Wsm[tx * 4 + j][k];
    #pragma unroll
    for (int i = 0; i < 4; ++i)
      #pragma unroll
      for (int j = 0; j < 4; ++j) acc[i][j] += av[i] * bv[j];
  }
  #pragma unroll
  for (int i = 0; i < 4; ++i) {
    int row = m0 + ty * 4 + i;
    float seed = seedbase + ((smask[row] == 0) ? 0.25f : 0.f);
    #pragma unroll
    for (int j = 0; j < 4; ++j) {
      int o = g * DK + tx * 4 + j;
      size_t idx = (size_t)row * CH + o;
      float v = fmaxf(acc[i][j] + bias[o], 0.f);
      out[idx] = v;
      out2[idx] = v * seed;
    }
  }
}

// top-4 insert, jax-stable tie-break (higher value first; equal value -> lower index)
__device__ inline void ins4(float v, int id, float tv[4], int tj[4]) {
  if (v < tv[3] || (v == tv[3] && id > tj[3])) return;
  tv[3] = v; tj[3] = id;
  #pragma unroll
  for (int k = 3; k > 0; --k) {
    bool sw = (tv[k] > tv[k - 1]) || (tv[k] == tv[k - 1] && tj[k] < tj[k - 1]);
    if (sw) {
      float fv = tv[k]; tv[k] = tv[k - 1]; tv[k - 1] = fv;
      int ti = tj[k]; tj[k] = tj[k - 1]; tj[k - 1] = ti;
    }
  }
}

// ---------------- per-row top-4 within a 256-col j-chunk (bf16 MFMA) ----------------
// Ranking: v = relu(dot * rnj) -- same order & zero-ties as relu(dot/(ni*nj)).
__global__ __launch_bounds__(256) void topk_part_kernel(
    const float* __restrict__ x, const float* __restrict__ rn,
    float* __restrict__ candV, int* __restrict__ candI) {
  __shared__ __align__(16) float cV[64][65];     // overlaid: Xj tile during j-loop
  __shared__ unsigned short cI[64][66];
  bf (*Xj)[LDK] = (bf(*)[LDK])cV;                // 9216 B <= 16640 B, safe overlay
  const int b = blockIdx.z, h = blockIdx.y;
  const int it = blockIdx.x >> 2, jc = blockIdx.x & 3;
  const int i0 = it * 64;
  const int tid = threadIdx.x, lane = tid & 63, w = tid >> 6;
  const int m = lane & 15, quad = lane >> 4;

  short8 afrag[2];
  load_afrag(&x[((size_t)b * NUM + i0 + w * 16 + m) * CH + h * DK], quad, afrag);

  float tv[4][4]; int tj[4][4];
  #pragma unroll
  for (int r = 0; r < 4; ++r)
    #pragma unroll
    for (int q = 0; q < 4; ++q) { tv[r][q] = -1.f; tj[r][q] = 0xffff; }

  for (int jt = 0; jt < 4; ++jt) {
    int j0 = jc * 256 + jt * 64;
    __syncthreads();
    stage_tile(x, (size_t)b * NUM + j0, h * DK, CH, Xj, tid);
    __syncthreads();
    #pragma unroll
    for (int nt = 0; nt < 4; ++nt) {
      f32x4 acc = {0.f, 0.f, 0.f, 0.f};
      #pragma unroll
      for (int kb = 0; kb < 2; ++kb) {
        short8 bb = *(const short8*)&Xj[nt * 16 + m][kb * 32 + quad * 8];
        acc = __builtin_amdgcn_mfma_f32_16x16x32_bf16(afrag[kb], bb, acc, 0, 0, 0);
      }
      int j = j0 + nt * 16 + m;
      float rnj = rn[((size_t)b * NUM + j) * HEADS + h];
      #pragma unroll
      for (int r = 0; r < 4; ++r) {
        float v = fmaxf(acc[r] * rnj, 0.f);
        ins4(v, j, tv[r], tj[r]);
      }
    }
  }
  __syncthreads();  // Xj dead; reuse memory as cV/cI
  #pragma unroll
  for (int r = 0; r < 4; ++r)
    #pragma unroll
    for (int q = 0; q < 4; ++q) {
      cV[w * 16 + quad * 4 + r][m * 4 + q] = tv[r][q];
      cI[w * 16 + quad * 4 + r][m * 4 + q] = (unsigned short)tj[r][q];
    }
  __syncthreads();
  if (tid < 64) {
    float fv[4] = {-1.f, -1.f, -1.f, -1.f};
    int fi[4] = {0x7fffffff, 0x7fffffff, 0x7fffffff, 0x7fffffff};
    for (int q = 0; q < 64; ++q) ins4(cV[tid][q], (int)cI[tid][q], fv, fi);
    size_t base = (size_t)((((b * HEADS + h) * 16 + it) * NJC + jc) * 64 + tid) * 4;
    #pragma unroll
    for (int q = 0; q < 4; ++q) { candV[base + q] = fv[q]; candI[base + q] = fi[q]; }
  }
}

// ---------------- merge NJC chunk candidates per row -> union into vec ----------------
__global__ __launch_bounds__(256) void topk_merge_kernel(
    const float* __restrict__ candV, const int* __restrict__ candI,
    float* __restrict__ vec) {
  int t = blockIdx.x * 256 + threadIdx.x;   // t = bhit*64 + rl
  int bhit = t >> 6, rl = t & 63;
  float fv[4] = {-1.f, -1.f, -1.f, -1.f};
  int fi[4] = {0x7fffffff, 0x7fffffff, 0x7fffffff, 0x7fffffff};
  #pragma unroll
  for (int jc = 0; jc < NJC; ++jc) {
    size_t base = (size_t)(((bhit) * NJC + jc) * 64 + rl) * 4;
    #pragma unroll
    for (int q = 0; q < 4; ++q) ins4(candV[base + q], candI[base + q], fv, fi);
  }
  #pragma unroll
  for (int q = 0; q < 4; ++q) vec[fi[q]] = 1.0f;  // benign race, all write 1
}

// ---------------- masked attention apply (bf16 MFMA scores + PV), j-chunked ----------------
// Ws[i][j] = pkbit(i,j) * relu(cos_ij)*0.25 ; PV uses vec-masked conv^T tile.
// Diagonal f_mask term is pre-seeded into `out` by conv_kernel.
// Per-wave Ws stripe: scores->PV needs no barrier (same-wave LDS ordering).
__global__ __launch_bounds__(256) void apply_kernel(
    const float* __restrict__ x, const float* __restrict__ conv,
    float* __restrict__ out, const float* __restrict__ rn,
    const float* __restrict__ vec, const u64* __restrict__ pk) {
  __shared__ __align__(16) bf Xj[64][LDK];
  __shared__ __align__(16) bf Cv[64][LDK];
  __shared__ __align__(16) bf Ws[64][LDK];
  const int b = blockIdx.z, h = blockIdx.y;
  const int it = blockIdx.x >> 2, jc = blockIdx.x & 3;
  const int i0 = it * 64;
  const int tid = threadIdx.x, lane = tid & 63, w = tid >> 6;
  const int m = lane & 15, quad = lane >> 4;

  short8 afrag[2];
  load_afrag(&x[((size_t)b * NUM + i0 + w * 16 + m) * CH + h * DK], quad, afrag);

  float rni4[4];
  #pragma unroll
  for (int r = 0; r < 4; ++r) {
    int row = i0 + w * 16 + quad * 4 + r;
    rni4[r] = 0.25f * rn[((size_t)b * NUM + row) * HEADS + h];
  }
  f32x4 om[4] = {{0.f,0.f,0.f,0.f},{0.f,0.f,0.f,0.f},{0.f,0.f,0.f,0.f},{0.f,0.f,0.f,0.f}};

  for (int jt = 0; jt < 4; ++jt) {
    int j0 = jc * 256 + jt * 64;
    __syncthreads();   // protect Xj/Cv from previous iteration's readers
    stage_tile(x, (size_t)b * NUM + j0, h * DK, CH, Xj, tid);
    {  // vec-masked conv^T tile
      int jr = tid >> 4, c4 = tid & 15;
      #pragma unroll
      for (int itt = 0; itt < 4; ++itt) {
        int j = jr + itt * 16;
        float vm = vec[j0 + j];
        const float4 v = *(const float4*)&conv[((size_t)b * NUM + j0 + j) * CH + h * DK + c4 * 4];
        Cv[c4 * 4 + 0][j] = tobf(v.x * vm);
        Cv[c4 * 4 + 1][j] = tobf(v.y * vm);
        Cv[c4 * 4 + 2][j] = tobf(v.z * vm);
        Cv[c4 * 4 + 3][j] = tobf(v.w * vm);
      }
    }
    u64 wr[4];
    #pragma unroll
    for (int r = 0; r < 4; ++r)
      wr[r] = pk[((size_t)b * NUM + i0 + w * 16 + quad * 4 + r) * 16 + (j0 >> 6)];
    __syncthreads();
    // scores -> masked weights -> Ws (own wave's 16-row stripe only)
    #pragma unroll
    for (int nt = 0; nt < 4; ++nt) {
      f32x4 acc = {0.f, 0.f, 0.f, 0.f};
      #pragma unroll
      for (int kb = 0; kb < 2; ++kb) {
        short8 bb = *(const short8*)&Xj[nt * 16 + m][kb * 32 + quad * 8];
        acc = __builtin_amdgcn_mfma_f32_16x16x32_bf16(afrag[kb], bb, acc, 0, 0, 0);
      }
      float rnj = rn[((size_t)b * NUM + j0 + nt * 16 + m) * HEADS + h];
      #pragma unroll
      for (int r = 0; r < 4; ++r) {
        float a = fmaxf(acc[r] * rni4[r] * rnj, 0.f);
        bool bit = (wr[r] >> (nt * 16 + m)) & 1ull;
        Ws[w * 16 + quad * 4 + r][nt * 16 + m] = tobf(bit ? a : 0.f);
      }
    }
    // PV: same-wave Ws stripe + Cv (stable until next loop-top barrier)
    #pragma unroll
    for (int kb = 0; kb < 2; ++kb) {
      short8 a = *(const short8*)&Ws[w * 16 + m][kb * 32 + quad * 8];
      #pragma unroll
      for (int ct = 0; ct < 4; ++ct) {
        short8 bb = *(const short8*)&Cv[ct * 16 + m][kb * 32 + quad * 8];
        om[ct] = __builtin_amdgcn_mfma_f32_16x16x32_bf16(a, bb, om[ct], 0, 0, 0);
      }
    }
  }
  #pragma unroll
  for (int ct = 0; ct < 4; ++ct)
    #pragma unroll
    for (int r = 0; r < 4; ++r) {
      size_t idx = ((size_t)b * NUM + i0 + w * 16 + quad * 4 + r) * CH + h * DK + ct * 16 + m;
      atomicAdd(&out[idx], om[ct][r]);
    }
}

// ---------------- LayerNorm + final outputs (in-place on d_out regions) ----------------
__global__ __launch_bounds__(256) void final_kernel(
    float* __restrict__ ybnf, float* __restrict__ out0,
    const float* __restrict__ lnw, const float* __restrict__ lnb) {
  __shared__ float r1[4];
  __shared__ float r2[4];
  int bn = blockIdx.x;
  int c = threadIdx.x;
  size_t idx = (size_t)bn * CH + c;
  float y = ybnf[idx];
  float x2v = out0[idx];
  float s = y;
  #pragma unroll
  for (int off = 32; off; off >>= 1) s += __shfl_down(s, off, 64);
  int wave = c >> 6, lane = c & 63;
  if (lane == 0) r1[wave] = s;
  __syncthreads();
  float mu = (r1[0] + r1[1] + r1[2] + r1[3]) * (1.f / 256.f);
  float d = y - mu;
  float s2 = d * d;
  #pragma unroll
  for (int off = 32; off; off >>= 1) s2 += __shfl_down(s2, off, 64);
  if (lane == 0) r2[wave] = s2;
  __syncthreads();
  float var = (r2[0] + r2[1] + r2[2] + r2[3]) * (1.f / 256.f);
  float nf = d * rsqrtf(var + 1e-6f) * lnw[c] + lnb[c];
  ybnf[idx] = nf;
  out0[idx] = x2v + nf;
}

extern "C" void kernel_launch(void* const* d_in, const int* in_sizes, int n_in,
                              void* d_out, int out_size, void* d_ws, size_t ws_size,
                              hipStream_t stream) {
  const float* input = (const float*)d_in[0];
  const int* mroi = (const int*)d_in[1];
  const int* smask = (const int*)d_in[2];
  const float* gt_feat = (const float*)d_in[3];
  const float* w1 = (const float*)d_in[4];
  const float* b1 = (const float*)d_in[5];
  const float* w2 = (const float*)d_in[6];
  const float* b2 = (const float*)d_in[7];
  const float* gt_w = (const float*)d_in[8];
  const float* gt_b = (const float*)d_in[9];
  const float* lnw = (const float*)d_in[10];
  const float* lnb = (const float*)d_in[11];

  const size_t SEG = (size_t)B_ * NUM * CH;  // 1048576 elements
  float* out0 = (float*)d_out;     // finally: out2^T + node_feat ; interim: X2 (conv2)
  float* gts = out0 + SEG;         // gts output (final from the start)
  float* nfreg = out0 + 2 * SEG;   // finally: node_feat ; interim: X1 then Yb

  // ws: F1 4MB | RN 64KB | VEC 8KB | candV 1MB | candI 1MB | PK 512KB ~= 6.6 MB
  float* F1 = (float*)d_ws;
  float* RN = F1 + SEG;
  float* VEC1 = RN + (size_t)B_ * NUM * HEADS;
  float* VEC2 = VEC1 + NUM;
  float* candV = VEC2 + NUM;
  const size_t NCAND = (size_t)B_ * HEADS * 16 * NJC * 64 * 4;
  int* candI = (int*)(candV + NCAND);
  u64* PK = (u64*)(candI + NCAND);

  float* X1 = nfreg;  // conv1 output (F1 seeded = X1*(1+0.25*[sm==0]))
  float* X2 = out0;   // conv2 output lives in out0 region until final_kernel
  float* Yb = nfreg;  // o2m accumulator (seeded = 0.25*[sm==0]*X2, overwrites dead X1)

  pack_kernel<<<1024, 256, 0, stream>>>(mroi, smask, PK, VEC1, VEC2);
  gts_kernel<<<dim3(64, 4), 256, 0, stream>>>(gt_feat, gt_w, gt_b, gts);

  // stage 1
  conv_kernel<<<dim3(64, 4), 256, 0, stream>>>(input, w1, b1, smask, 1.0f, X1, F1, RN);
  topk_part_kernel<<<dim3(16 * NJC, HEADS, B_), 256, 0, stream>>>(input, RN, candV, candI);
  topk_merge_kernel<<<64, 256, 0, stream>>>(candV, candI, VEC1);
  apply_kernel<<<dim3(16 * NJC, HEADS, B_), 256, 0, stream>>>(
      input, X1, F1, RN, VEC1, PK);

  // stage 2
  conv_kernel<<<dim3(64, 4), 256, 0, stream>>>(F1, w2, b2, smask, 0.0f, X2, Yb, RN);
  topk_part_kernel<<<dim3(16 * NJC, HEADS, B_), 256, 0, stream>>>(F1, RN, candV, candI);
  topk_merge_kernel<<<64, 256, 0, stream>>>(candV, candI, VEC2);
  apply_kernel<<<dim3(16 * NJC, HEADS, B_), 256, 0, stream>>>(
      F1, X2, Yb, RN, VEC2, PK);

  final_kernel<<<4096, 256, 0, stream>>>(Yb, X2, lnw, lnb);
}